// Round 10
// baseline (266.419 us; speedup 1.0000x reference)
//
#include <hip/hip_runtime.h>
#include <math.h>

#define N_NODES 50000
#define N_EDGES 262144

using short8  = __attribute__((ext_vector_type(8))) short;
using f32x4   = __attribute__((ext_vector_type(4))) float;
using u16x4   = __attribute__((ext_vector_type(4))) unsigned short;
using u16x8   = __attribute__((ext_vector_type(8))) unsigned short;
using uint4v  = __attribute__((ext_vector_type(4))) unsigned int;

// ---------------------------------------------------------------------------
// bf16 helpers (RNE)
// ---------------------------------------------------------------------------
__device__ __forceinline__ ushort bf16_rne(float x) {
    uint u = __float_as_uint(x);
    uint r = (u + 0x7FFFu + ((u >> 16) & 1u)) >> 16;
    return (ushort)r;
}

struct WtDesc { const float* W; ushort* hi; int K, N, KP, NP; };
struct WtDescs { WtDesc d[6]; };

// ---------------------------------------------------------------------------
// Fused setup: zero cursor+blockState | convert W (hi) | convert features (hi)
// ---------------------------------------------------------------------------
__global__ __launch_bounds__(256) void setup_fused(int* __restrict__ cursor,
                                                   int* __restrict__ blockState,
                                                   WtDescs all,
                                                   const float* __restrict__ X,
                                                   ushort* __restrict__ hi) {
    const int b = blockIdx.x;
    const int t = threadIdx.x;
    if (b < 196) {
        int i = b * 256 + t;
        if (i < N_NODES) cursor[i] = 0;
        if (b == 0 && t < 64) blockState[t] = 0;
    } else if (b < 2116) {
        int bb = b - 196;
        WtDesc d = all.d[bb / 320];
        int total = d.NP * d.KP;
        for (int idx = (bb % 320) * 256 + t; idx < total; idx += 320 * 256) {
            int n = idx / d.KP;
            int k = idx - n * d.KP;
            float v = (n < d.N && k < d.K) ? d.W[(size_t)k * d.N + n] : 0.f;
            d.hi[idx] = bf16_rne(v);
        }
    } else {
        int idx = (b - 2116) * 256 + t;       // N_NODES*40 ushort8 jobs
        if (idx >= N_NODES * 40) return;
        int row = idx / 40;
        int c = idx - row * 40;
        u16x8 h8 = {0, 0, 0, 0, 0, 0, 0, 0};
        const float* xr = X + (size_t)row * 300 + c * 8;
        if (c < 37) {
            float4 v0 = *(const float4*)(const void*)(xr);
            float4 v1 = *(const float4*)(const void*)(xr + 4);
            h8[0] = bf16_rne(v0.x); h8[1] = bf16_rne(v0.y);
            h8[2] = bf16_rne(v0.z); h8[3] = bf16_rne(v0.w);
            h8[4] = bf16_rne(v1.x); h8[5] = bf16_rne(v1.y);
            h8[6] = bf16_rne(v1.z); h8[7] = bf16_rne(v1.w);
        } else if (c == 37) {
            float4 v0 = *(const float4*)(const void*)(xr);  // cols 296..299
            h8[0] = bf16_rne(v0.x); h8[1] = bf16_rne(v0.y);
            h8[2] = bf16_rne(v0.z); h8[3] = bf16_rne(v0.w);
        }
        *(u16x8*)(void*)(hi + (size_t)row * 320 + c * 8) = h8;
    }
}

// ---------------------------------------------------------------------------
// CSR build
// ---------------------------------------------------------------------------
__global__ void count_kernel(const int* __restrict__ dst, int* __restrict__ deg, int E) {
    int e = blockIdx.x * 256 + threadIdx.x;
    if (e < E) atomicAdd(&deg[dst[e]], 1);
}

__global__ __launch_bounds__(256) void scan_lookback(const int* __restrict__ deg,
                                                     int* __restrict__ row_start,
                                                     int* __restrict__ cursor,
                                                     int* __restrict__ blockState,
                                                     int n, int total) {
    __shared__ int wsum[4];
    __shared__ int s_off;
    const int b = blockIdx.x;
    const int t = threadIdx.x;
    const int i0 = b * 1024 + t * 4;
    int x0 = 0, x1 = 0, x2 = 0, x3 = 0;
    if (i0 + 3 < n) {
        int4 v = *(const int4*)(const void*)(deg + i0);
        x0 = v.x; x1 = v.y; x2 = v.z; x3 = v.w;
    } else {
        if (i0 + 0 < n) x0 = deg[i0 + 0];
        if (i0 + 1 < n) x1 = deg[i0 + 1];
        if (i0 + 2 < n) x2 = deg[i0 + 2];
        if (i0 + 3 < n) x3 = deg[i0 + 3];
    }
    int s = x0 + x1 + x2 + x3;
    int lane = t & 63;
    int wid = t >> 6;
    int incl = s;
    #pragma unroll
    for (int off = 1; off < 64; off <<= 1) {
        int u = __shfl_up(incl, off);
        if (lane >= off) incl += u;
    }
    if (lane == 63) wsum[wid] = incl;
    __syncthreads();
    int woff = 0;
    #pragma unroll
    for (int k = 0; k < 4; ++k)
        if (k < wid) woff += wsum[k];
    int texcl = woff + incl - s;

    if (t == 0) {
        int bs = wsum[0] + wsum[1] + wsum[2] + wsum[3];
        atomicExch(&blockState[b], (bs << 2) | 1);
        int off = 0;
        for (int pb = b - 1; pb >= 0; --pb) {
            int st;
            do { st = atomicAdd(&blockState[pb], 0); } while ((st & 3) == 0);
            off += (st >> 2);
            if ((st & 3) == 2) break;
        }
        atomicExch(&blockState[b], ((off + bs) << 2) | 2);
        s_off = off;
    }
    __syncthreads();
    int off = s_off;

    if (i0 + 3 < n) {
        int4 o;
        o.x = off + texcl;
        o.y = off + texcl + x0;
        o.z = off + texcl + x0 + x1;
        o.w = off + texcl + x0 + x1 + x2;
        *(int4*)(void*)(row_start + i0) = o;
        *(int4*)(void*)(cursor + i0) = o;
    } else {
        int vals[4] = {off + texcl, off + texcl + x0, off + texcl + x0 + x1,
                       off + texcl + x0 + x1 + x2};
        #pragma unroll
        for (int k = 0; k < 4; ++k)
            if (i0 + k < n) { row_start[i0 + k] = vals[k]; cursor[i0 + k] = vals[k]; }
    }
    if (b == 0 && t == 0) row_start[n] = total;
}

__global__ void fill_kernel(const int* __restrict__ src, const int* __restrict__ dst,
                            int* __restrict__ cursor, int* __restrict__ esrc, int E) {
    int e = blockIdx.x * 256 + threadIdx.x;
    if (e < E) {
        int d = dst[e];
        int pos = atomicAdd(&cursor[d], 1);
        esrc[pos] = src[e];
    }
}

// ---------------------------------------------------------------------------
// 1-term bf16 MFMA GEMM (layer 1: dense features). H out bf16, stride FP.
// ---------------------------------------------------------------------------
template <int KP, int NT>
__global__ __launch_bounds__(256) void gemm_bf16(const ushort* __restrict__ Ahi,
                                                 const ushort* __restrict__ Bhi,
                                                 ushort* __restrict__ Hb, int M, int FP) {
    __shared__ __align__(16) ushort AsH[128][40];
    __shared__ __align__(16) ushort BsH[NT * 16][40];

    constexpr int NK = KP / 32;
    constexpr int BCH = (NT * 64 + 255) / 256;

    const int tid = threadIdx.x;
    const int lane = tid & 63;
    const int w = tid >> 6;
    const int brow = blockIdx.x * 128;

    f32x4 acc[2][NT];
    #pragma unroll
    for (int mt = 0; mt < 2; ++mt)
        #pragma unroll
        for (int nt = 0; nt < NT; ++nt)
            acc[mt][nt] = (f32x4){0.f, 0.f, 0.f, 0.f};

    const int ar = tid >> 1;
    const int aq = (tid & 1) * 2;
    const bool arow_ok = (brow + ar) < M;
    const size_t arow_off = (size_t)(brow + ar) * KP;

    const short8 zz = {0, 0, 0, 0, 0, 0, 0, 0};
    short8 rAh[2], rBh[BCH];

    auto load_regs = [&](int kt) {
        const int k0 = kt * 32;
        #pragma unroll
        for (int qq = 0; qq < 2; ++qq) {
            int q = aq + qq;
            rAh[qq] = arow_ok ? *(const short8*)(const void*)(Ahi + arow_off + k0 + q * 8) : zz;
        }
        #pragma unroll
        for (int c = 0; c < BCH; ++c) {
            int i = tid + c * 256;
            if (i < NT * 64) {
                int r = i >> 2;
                int q = i & 3;
                rBh[c] = *(const short8*)(const void*)(Bhi + (size_t)r * KP + k0 + q * 8);
            }
        }
    };
    auto write_lds = [&]() {
        #pragma unroll
        for (int qq = 0; qq < 2; ++qq) {
            int q = aq + qq;
            *(short8*)(void*)&AsH[ar][q * 8] = rAh[qq];
        }
        #pragma unroll
        for (int c = 0; c < BCH; ++c) {
            int i = tid + c * 256;
            if (i < NT * 64) {
                int r = i >> 2;
                int q = i & 3;
                *(short8*)(void*)&BsH[r][q * 8] = rBh[c];
            }
        }
    };

    load_regs(0);
    for (int kt = 0; kt < NK; ++kt) {
        write_lds();
        __syncthreads();
        if (kt + 1 < NK) load_regs(kt + 1);

        const int fr = lane & 15;
        const int fk = (lane >> 4) * 8;
        short8 ah[2];
        #pragma unroll
        for (int mt = 0; mt < 2; ++mt)
            ah[mt] = *(const short8*)(const void*)&AsH[w * 32 + mt * 16 + fr][fk];
        #pragma unroll
        for (int nt = 0; nt < NT; ++nt) {
            short8 bh = *(const short8*)(const void*)&BsH[nt * 16 + fr][fk];
            #pragma unroll
            for (int mt = 0; mt < 2; ++mt)
                acc[mt][nt] = __builtin_amdgcn_mfma_f32_16x16x32_bf16(ah[mt], bh, acc[mt][nt], 0, 0, 0);
        }
        __syncthreads();
    }

    const int fr = lane & 15;
    const int fq = lane >> 4;
    #pragma unroll
    for (int mt = 0; mt < 2; ++mt)
        #pragma unroll
        for (int nt = 0; nt < NT; ++nt) {
            int col = nt * 16 + fr;
            if (col < FP) {
                #pragma unroll
                for (int r = 0; r < 4; ++r) {
                    int row = brow + w * 32 + mt * 16 + fq * 4 + r;
                    if (row < M) Hb[(size_t)row * FP + col] = bf16_rne(acc[mt][nt][r]);
                }
            }
        }
}

// ---------------------------------------------------------------------------
// FUSED: X = act(agg(Hin) + bias) built in LDS, then Hout = X @ W^T (MFMA).
// Block owns 64 nodes (rows). Gather phase: NSW=256/SW sub-waves fill A-LDS
// rows as bf16 (zero-padded to KP). GEMM phase: 4 waves x 16 rows x NT*16.
// ACT: 0 leaky, 1 softmax.
// ---------------------------------------------------------------------------
template <int ACT, int F, int FPIN, int KP, int SW, int NT, int FPOUT>
__global__ __launch_bounds__(256) void fused_agg_gemm(const ushort* __restrict__ Hin,
                                                      const int* __restrict__ row_start,
                                                      const int* __restrict__ esrc,
                                                      const float* __restrict__ bias,
                                                      const ushort* __restrict__ Bhi,
                                                      ushort* __restrict__ Hout, int M) {
    constexpr int CH = FPIN / 8;       // input chunks per row
    constexpr int NSW = 256 / SW;      // sub-waves per block
    constexpr int ROUNDS = 64 / NSW;
    constexpr int NK = KP / 32;
    constexpr int BCH = (NT * 64 + 255) / 256;
    static_assert(CH <= SW, "input chunks must fit sub-wave");
    static_assert(KP <= SW * 8, "A zero-fill must cover KP");

    __shared__ __align__(16) ushort As[64][KP + 8];
    __shared__ __align__(16) ushort Bs[NT * 16][40];

    const int t = threadIdx.x;
    const int brow = blockIdx.x * 64;

    // ---------------- gather + activation phase ----------------
    {
        const int subIdx = t / SW;
        const int subl = t - subIdx * SW;
        const bool al = subl < CH;
        const int jb = subl * 8;
        const uint4v* Hc = (const uint4v*)Hin;

        #define ACCUM(rr)                                            \
            {                                                        \
                _Pragma("unroll")                                    \
                for (int k = 0; k < 4; ++k) {                        \
                    uint u = (rr)[k];                                \
                    a[2 * k]     += __uint_as_float(u << 16);        \
                    a[2 * k + 1] += __uint_as_float(u & 0xFFFF0000u);\
                }                                                    \
            }

        for (int rnd = 0; rnd < ROUNDS; ++rnd) {
            const int lrow = rnd * NSW + subIdx;
            const int v = brow + lrow;
            float a[8] = {0.f, 0.f, 0.f, 0.f, 0.f, 0.f, 0.f, 0.f};
            float res[8] = {0.f, 0.f, 0.f, 0.f, 0.f, 0.f, 0.f, 0.f};

            if (v < M) {
                const int e0 = row_start[v];
                const int e1 = row_start[v + 1];
                int e = e0;
                for (; e + 8 <= e1; e += 8) {
                    int s0 = esrc[e + 0], s1 = esrc[e + 1], s2 = esrc[e + 2], s3 = esrc[e + 3];
                    int s4 = esrc[e + 4], s5 = esrc[e + 5], s6 = esrc[e + 6], s7 = esrc[e + 7];
                    if (al) {
                        uint4v r0 = Hc[(size_t)s0 * CH + subl];
                        uint4v r1 = Hc[(size_t)s1 * CH + subl];
                        uint4v r2 = Hc[(size_t)s2 * CH + subl];
                        uint4v r3 = Hc[(size_t)s3 * CH + subl];
                        uint4v r4 = Hc[(size_t)s4 * CH + subl];
                        uint4v r5 = Hc[(size_t)s5 * CH + subl];
                        uint4v r6 = Hc[(size_t)s6 * CH + subl];
                        uint4v r7 = Hc[(size_t)s7 * CH + subl];
                        ACCUM(r0) ACCUM(r1) ACCUM(r2) ACCUM(r3)
                        ACCUM(r4) ACCUM(r5) ACCUM(r6) ACCUM(r7)
                    }
                }
                if (e + 4 <= e1) {
                    int s0 = esrc[e + 0], s1 = esrc[e + 1], s2 = esrc[e + 2], s3 = esrc[e + 3];
                    if (al) {
                        uint4v r0 = Hc[(size_t)s0 * CH + subl];
                        uint4v r1 = Hc[(size_t)s1 * CH + subl];
                        uint4v r2 = Hc[(size_t)s2 * CH + subl];
                        uint4v r3 = Hc[(size_t)s3 * CH + subl];
                        ACCUM(r0) ACCUM(r1) ACCUM(r2) ACCUM(r3)
                    }
                    e += 4;
                }
                for (; e < e1; ++e) {
                    int s = esrc[e];
                    if (al) {
                        uint4v r = Hc[(size_t)s * CH + subl];
                        ACCUM(r)
                    }
                }

                #pragma unroll
                for (int k = 0; k < 8; ++k) {
                    int j = jb + k;
                    a[k] += (al && j < F) ? bias[j] : 0.f;
                }

                if (ACT == 0) {
                    #pragma unroll
                    for (int k = 0; k < 8; ++k)
                        res[k] = (a[k] >= 0.f) ? a[k] : 0.01f * a[k];
                } else {
                    float m = -INFINITY;
                    #pragma unroll
                    for (int k = 0; k < 8; ++k) {
                        int j = jb + k;
                        if (al && j < F) m = fmaxf(m, a[k]);
                    }
                    #pragma unroll
                    for (int off = SW / 2; off > 0; off >>= 1) m = fmaxf(m, __shfl_xor(m, off));
                    float p[8];
                    float ssum = 0.f;
                    #pragma unroll
                    for (int k = 0; k < 8; ++k) {
                        int j = jb + k;
                        if (al && j < F) { p[k] = expf(a[k] - m); ssum += p[k]; } else p[k] = 0.f;
                    }
                    #pragma unroll
                    for (int off = SW / 2; off > 0; off >>= 1) ssum += __shfl_xor(ssum, off);
                    float inv = 1.f / ssum;
                    #pragma unroll
                    for (int k = 0; k < 8; ++k) res[k] = p[k] * inv;
                }
            }

            // write activated bf16 row into A-LDS (zeros beyond F / beyond M)
            if (jb < KP) {
                u16x8 h8;
                #pragma unroll
                for (int k = 0; k < 8; ++k) {
                    int j = jb + k;
                    h8[k] = bf16_rne((al && j < F) ? res[k] : 0.f);
                }
                *(u16x8*)(void*)&As[lrow][jb] = h8;
            }
        }
        #undef ACCUM
    }
    __syncthreads();

    // ---------------- GEMM phase ----------------
    const int lane = t & 63;
    const int w = t >> 6;

    f32x4 acc[NT];
    #pragma unroll
    for (int nt = 0; nt < NT; ++nt)
        acc[nt] = (f32x4){0.f, 0.f, 0.f, 0.f};

    short8 rBh[BCH];
    auto load_regs = [&](int kt) {
        const int k0 = kt * 32;
        #pragma unroll
        for (int c = 0; c < BCH; ++c) {
            int i = t + c * 256;
            if (i < NT * 64) {
                int r = i >> 2;
                int q = i & 3;
                rBh[c] = *(const short8*)(const void*)(Bhi + (size_t)r * KP + k0 + q * 8);
            }
        }
    };
    auto write_lds = [&]() {
        #pragma unroll
        for (int c = 0; c < BCH; ++c) {
            int i = t + c * 256;
            if (i < NT * 64) {
                int r = i >> 2;
                int q = i & 3;
                *(short8*)(void*)&Bs[r][q * 8] = rBh[c];
            }
        }
    };

    load_regs(0);
    for (int kt = 0; kt < NK; ++kt) {
        write_lds();
        __syncthreads();
        if (kt + 1 < NK) load_regs(kt + 1);

        const int fr = lane & 15;
        const int fk = (lane >> 4) * 8;
        short8 ah = *(const short8*)(const void*)&As[w * 16 + fr][kt * 32 + fk];
        #pragma unroll
        for (int nt = 0; nt < NT; ++nt) {
            short8 bh = *(const short8*)(const void*)&Bs[nt * 16 + fr][fk];
            acc[nt] = __builtin_amdgcn_mfma_f32_16x16x32_bf16(ah, bh, acc[nt], 0, 0, 0);
        }
        __syncthreads();
    }

    const int fr = lane & 15;
    const int fq = lane >> 4;
    #pragma unroll
    for (int nt = 0; nt < NT; ++nt) {
        int col = nt * 16 + fr;
        if (col < FPOUT) {
            #pragma unroll
            for (int r = 0; r < 4; ++r) {
                int row = brow + w * 16 + fq * 4 + r;
                if (row < M) Hout[(size_t)row * FPOUT + col] = bf16_rne(acc[nt][r]);
            }
        }
    }
}

// ---------------------------------------------------------------------------
// Final aggregation + log_softmax -> f32 d_out (layer 6 tail).
// ---------------------------------------------------------------------------
template <int F, int FP, int SW>
__global__ __launch_bounds__(256) void agg_logsm(const ushort* __restrict__ Hb,
                                                 const int* __restrict__ row_start,
                                                 const int* __restrict__ esrc,
                                                 const float* __restrict__ bias,
                                                 float* __restrict__ outF) {
    constexpr int CH = FP / 8;
    constexpr int NPB = 256 / SW;
    static_assert(CH <= SW, "chunks must fit sub-wave");

    const int t = threadIdx.x;
    const int sub = t / SW;
    const int subl = t - sub * SW;
    const int v = blockIdx.x * NPB + sub;
    if (v >= N_NODES) return;

    const int e0 = row_start[v];
    const int e1 = row_start[v + 1];
    const bool al = subl < CH;
    const uint4v* Hc = (const uint4v*)Hb;

    float a[8] = {0.f, 0.f, 0.f, 0.f, 0.f, 0.f, 0.f, 0.f};

    #define ACCUM(rr)                                            \
        {                                                        \
            _Pragma("unroll")                                    \
            for (int k = 0; k < 4; ++k) {                        \
                uint u = (rr)[k];                                \
                a[2 * k]     += __uint_as_float(u << 16);        \
                a[2 * k + 1] += __uint_as_float(u & 0xFFFF0000u);\
            }                                                    \
        }

    int e = e0;
    for (; e + 8 <= e1; e += 8) {
        int s0 = esrc[e + 0], s1 = esrc[e + 1], s2 = esrc[e + 2], s3 = esrc[e + 3];
        int s4 = esrc[e + 4], s5 = esrc[e + 5], s6 = esrc[e + 6], s7 = esrc[e + 7];
        if (al) {
            uint4v r0 = Hc[(size_t)s0 * CH + subl];
            uint4v r1 = Hc[(size_t)s1 * CH + subl];
            uint4v r2 = Hc[(size_t)s2 * CH + subl];
            uint4v r3 = Hc[(size_t)s3 * CH + subl];
            uint4v r4 = Hc[(size_t)s4 * CH + subl];
            uint4v r5 = Hc[(size_t)s5 * CH + subl];
            uint4v r6 = Hc[(size_t)s6 * CH + subl];
            uint4v r7 = Hc[(size_t)s7 * CH + subl];
            ACCUM(r0) ACCUM(r1) ACCUM(r2) ACCUM(r3)
            ACCUM(r4) ACCUM(r5) ACCUM(r6) ACCUM(r7)
        }
    }
    if (e + 4 <= e1) {
        int s0 = esrc[e + 0], s1 = esrc[e + 1], s2 = esrc[e + 2], s3 = esrc[e + 3];
        if (al) {
            uint4v r0 = Hc[(size_t)s0 * CH + subl];
            uint4v r1 = Hc[(size_t)s1 * CH + subl];
            uint4v r2 = Hc[(size_t)s2 * CH + subl];
            uint4v r3 = Hc[(size_t)s3 * CH + subl];
            ACCUM(r0) ACCUM(r1) ACCUM(r2) ACCUM(r3)
        }
        e += 4;
    }
    for (; e < e1; ++e) {
        int s = esrc[e];
        if (al) {
            uint4v r = Hc[(size_t)s * CH + subl];
            ACCUM(r)
        }
    }
    #undef ACCUM

    const int jb = subl * 8;
    #pragma unroll
    for (int k = 0; k < 8; ++k) {
        int j = jb + k;
        a[k] += (al && j < F) ? bias[j] : 0.f;
    }

    float m = -INFINITY;
    #pragma unroll
    for (int k = 0; k < 8; ++k) {
        int j = jb + k;
        if (al && j < F) m = fmaxf(m, a[k]);
    }
    if (SW > 1) {
        #pragma unroll
        for (int off = SW / 2; off > 0; off >>= 1) m = fmaxf(m, __shfl_xor(m, off));
    }
    float ssum = 0.f;
    #pragma unroll
    for (int k = 0; k < 8; ++k) {
        int j = jb + k;
        if (al && j < F) ssum += expf(a[k] - m);
    }
    if (SW > 1) {
        #pragma unroll
        for (int off = SW / 2; off > 0; off >>= 1) ssum += __shfl_xor(ssum, off);
    }
    float ls = logf(ssum);

    float* orow = outF + (size_t)v * F;
    #pragma unroll
    for (int k = 0; k < 8; ++k) {
        int j = jb + k;
        if (al && j < F) orow[j] = a[k] - m - ls;
    }
}

// ---------------------------------------------------------------------------
// Host launch
// ---------------------------------------------------------------------------
static inline size_t align_up(size_t x, size_t a) { return (x + a - 1) & ~(a - 1); }

extern "C" void kernel_launch(void* const* d_in, const int* in_sizes, int n_in,
                              void* d_out, int out_size, void* d_ws, size_t ws_size,
                              hipStream_t stream) {
    const float* features = (const float*)d_in[0];
    const int* src = (const int*)d_in[1];
    const int* dst = (const int*)d_in[2];
    const float* W[6];
    const float* b[6];
    for (int l = 0; l < 6; ++l) {
        W[l] = (const float*)d_in[3 + 2 * l];
        b[l] = (const float*)d_in[4 + 2 * l];
    }

    const int fout[6] = {200, 150, 100, 50, 25, 3};
    const int KPin[6] = {320, 224, 160, 128, 64, 32};
    const int NPl[6]  = {208, 160, 112, 64, 32, 16};   // NT*16

    // workspace layout
    char* ws = (char*)d_ws;
    size_t off = 0;
    int* row_start  = (int*)(ws + off); off = align_up(off + (N_NODES + 1) * sizeof(int), 256);
    int* cursor     = (int*)(ws + off); off = align_up(off + (N_NODES + 1) * sizeof(int), 256);
    int* esrc       = (int*)(ws + off); off = align_up(off + N_EDGES * sizeof(int), 256);
    int* blockState = (int*)(ws + off); off = align_up(off + 64 * sizeof(int), 256);
    ushort* Wthi[6];
    for (int l = 0; l < 6; ++l) {
        Wthi[l] = (ushort*)(ws + off); off = align_up(off + (size_t)NPl[l] * KPin[l] * 2, 256);
    }
    ushort* Xhi = (ushort*)(ws + off); off = align_up(off + (size_t)N_NODES * 320 * 2, 256);
    ushort* HbA = (ushort*)(ws + off); off = align_up(off + (size_t)N_NODES * 200 * 2, 256);
    ushort* HbB = (ushort*)(ws + off); off = align_up(off + (size_t)N_NODES * 152 * 2, 256);
    (void)ws_size;

    // --- fused setup ---
    {
        WtDescs wd;
        const int fin[6] = {300, 200, 150, 100, 50, 25};
        for (int l = 0; l < 6; ++l)
            wd.d[l] = WtDesc{W[l], Wthi[l], fin[l], fout[l], KPin[l], NPl[l]};
        setup_fused<<<2116 + (N_NODES * 40 + 255) / 256, 256, 0, stream>>>(
            cursor, blockState, wd, features, Xhi);
    }

    // --- CSR build ---
    count_kernel<<<(N_EDGES + 255) / 256, 256, 0, stream>>>(dst, cursor, N_EDGES);
    scan_lookback<<<(N_NODES + 1023) / 1024, 256, 0, stream>>>(cursor, row_start, cursor,
                                                               blockState, N_NODES, N_EDGES);
    fill_kernel<<<(N_EDGES + 255) / 256, 256, 0, stream>>>(src, dst, cursor, esrc, N_EDGES);

    const int gy = (N_NODES + 127) / 128;  // 391
    const int gf = (N_NODES + 63) / 64;    // 782

    // L1 GEMM: H1 = Xfeat @ W1  (FP 200)
    gemm_bf16<320, 13><<<gy, 256, 0, stream>>>(Xhi, Wthi[0], HbA, N_NODES, 200);

    // F1 = agg(H1)+b1, leaky | @W2 -> H2 (FP 152)
    fused_agg_gemm<0, 200, 200, 224, 32, 10, 152><<<gf, 256, 0, stream>>>(
        HbA, row_start, esrc, b[0], Wthi[1], HbB, N_NODES);

    // F2 = agg(H2)+b2, softmax | @W3 -> H3 (FP 104)
    fused_agg_gemm<1, 150, 152, 160, 32, 7, 104><<<gf, 256, 0, stream>>>(
        HbB, row_start, esrc, b[1], Wthi[2], HbA, N_NODES);

    // F3 = agg(H3)+b3, leaky | @W4 -> H4 (FP 56)
    fused_agg_gemm<0, 100, 104, 128, 16, 4, 56><<<gf, 256, 0, stream>>>(
        HbA, row_start, esrc, b[2], Wthi[3], HbB, N_NODES);

    // F4 = agg(H4)+b4, softmax | @W5 -> H5 (FP 32)
    fused_agg_gemm<1, 50, 56, 64, 8, 2, 32><<<gf, 256, 0, stream>>>(
        HbB, row_start, esrc, b[3], Wthi[4], HbA, N_NODES);

    // F5 = agg(H5)+b5, leaky | @W6 -> H6 (FP 8)
    fused_agg_gemm<0, 25, 32, 32, 4, 1, 8><<<gf, 256, 0, stream>>>(
        HbA, row_start, esrc, b[4], Wthi[5], HbB, N_NODES);

    // final: out = log_softmax(agg(H6) + b6)
    agg_logsm<3, 8, 1><<<(N_NODES + 255) / 256, 256, 0, stream>>>(
        HbB, row_start, esrc, b[5], (float*)d_out);

    (void)out_size; (void)n_in; (void)in_sizes;
}

// Round 11
// 261.429 us; speedup vs baseline: 1.0191x; 1.0191x over previous
//
#include <hip/hip_runtime.h>
#include <math.h>

#define N_NODES 50000
#define N_EDGES 262144

using short8  = __attribute__((ext_vector_type(8))) short;
using f32x4   = __attribute__((ext_vector_type(4))) float;
using u16x4   = __attribute__((ext_vector_type(4))) unsigned short;
using u16x8   = __attribute__((ext_vector_type(8))) unsigned short;
using uint4v  = __attribute__((ext_vector_type(4))) unsigned int;

// ---------------------------------------------------------------------------
// bf16 helpers (RNE)
// ---------------------------------------------------------------------------
__device__ __forceinline__ ushort bf16_rne(float x) {
    uint u = __float_as_uint(x);
    uint r = (u + 0x7FFFu + ((u >> 16) & 1u)) >> 16;
    return (ushort)r;
}

struct WtDesc { const float* W; ushort* hi; int K, N, KP, NP; };
struct WtDescs { WtDesc d[6]; };

// ---------------------------------------------------------------------------
// Fused setup: zero cursor+blockState | convert W (hi). Features are NOT
// pre-converted — gemm_l1 reads f32 features directly (saves 64 MB traffic).
// blocks [0,196): zero; [196,2116): convert_w
// ---------------------------------------------------------------------------
__global__ __launch_bounds__(256) void setup_fused(int* __restrict__ cursor,
                                                   int* __restrict__ blockState,
                                                   WtDescs all) {
    const int b = blockIdx.x;
    const int t = threadIdx.x;
    if (b < 196) {
        int i = b * 256 + t;
        if (i < N_NODES) cursor[i] = 0;
        if (b == 0 && t < 64) blockState[t] = 0;
    } else {
        int bb = b - 196;
        WtDesc d = all.d[bb / 320];
        int total = d.NP * d.KP;
        for (int idx = (bb % 320) * 256 + t; idx < total; idx += 320 * 256) {
            int n = idx / d.KP;
            int k = idx - n * d.KP;
            float v = (n < d.N && k < d.K) ? d.W[(size_t)k * d.N + n] : 0.f;
            d.hi[idx] = bf16_rne(v);
        }
    }
}

// ---------------------------------------------------------------------------
// CSR build
// ---------------------------------------------------------------------------
__global__ void count_kernel(const int* __restrict__ dst, int* __restrict__ deg, int E) {
    int e = blockIdx.x * 256 + threadIdx.x;
    if (e < E) atomicAdd(&deg[dst[e]], 1);
}

__global__ __launch_bounds__(256) void scan_lookback(const int* __restrict__ deg,
                                                     int* __restrict__ row_start,
                                                     int* __restrict__ cursor,
                                                     int* __restrict__ blockState,
                                                     int n, int total) {
    __shared__ int wsum[4];
    __shared__ int s_off;
    const int b = blockIdx.x;
    const int t = threadIdx.x;
    const int i0 = b * 1024 + t * 4;
    int x0 = 0, x1 = 0, x2 = 0, x3 = 0;
    if (i0 + 3 < n) {
        int4 v = *(const int4*)(const void*)(deg + i0);
        x0 = v.x; x1 = v.y; x2 = v.z; x3 = v.w;
    } else {
        if (i0 + 0 < n) x0 = deg[i0 + 0];
        if (i0 + 1 < n) x1 = deg[i0 + 1];
        if (i0 + 2 < n) x2 = deg[i0 + 2];
        if (i0 + 3 < n) x3 = deg[i0 + 3];
    }
    int s = x0 + x1 + x2 + x3;
    int lane = t & 63;
    int wid = t >> 6;
    int incl = s;
    #pragma unroll
    for (int off = 1; off < 64; off <<= 1) {
        int u = __shfl_up(incl, off);
        if (lane >= off) incl += u;
    }
    if (lane == 63) wsum[wid] = incl;
    __syncthreads();
    int woff = 0;
    #pragma unroll
    for (int k = 0; k < 4; ++k)
        if (k < wid) woff += wsum[k];
    int texcl = woff + incl - s;

    if (t == 0) {
        int bs = wsum[0] + wsum[1] + wsum[2] + wsum[3];
        atomicExch(&blockState[b], (bs << 2) | 1);
        int off = 0;
        for (int pb = b - 1; pb >= 0; --pb) {
            int st;
            do { st = atomicAdd(&blockState[pb], 0); } while ((st & 3) == 0);
            off += (st >> 2);
            if ((st & 3) == 2) break;
        }
        atomicExch(&blockState[b], ((off + bs) << 2) | 2);
        s_off = off;
    }
    __syncthreads();
    int off = s_off;

    if (i0 + 3 < n) {
        int4 o;
        o.x = off + texcl;
        o.y = off + texcl + x0;
        o.z = off + texcl + x0 + x1;
        o.w = off + texcl + x0 + x1 + x2;
        *(int4*)(void*)(row_start + i0) = o;
        *(int4*)(void*)(cursor + i0) = o;
    } else {
        int vals[4] = {off + texcl, off + texcl + x0, off + texcl + x0 + x1,
                       off + texcl + x0 + x1 + x2};
        #pragma unroll
        for (int k = 0; k < 4; ++k)
            if (i0 + k < n) { row_start[i0 + k] = vals[k]; cursor[i0 + k] = vals[k]; }
    }
    if (b == 0 && t == 0) row_start[n] = total;
}

__global__ void fill_kernel(const int* __restrict__ src, const int* __restrict__ dst,
                            int* __restrict__ cursor, int* __restrict__ esrc, int E) {
    int e = blockIdx.x * 256 + threadIdx.x;
    if (e < E) {
        int d = dst[e];
        int pos = atomicAdd(&cursor[d], 1);
        esrc[pos] = src[e];
    }
}

// ---------------------------------------------------------------------------
// Layer-1 GEMM: A = f32 features [M][300], converted to bf16 in-register
// during staging (K zero-padded to 320). B = Wthi[0] [NT*16][320] bf16.
// ---------------------------------------------------------------------------
template <int NT>
__global__ __launch_bounds__(256) void gemm_l1(const float* __restrict__ Af,
                                               const ushort* __restrict__ Bhi,
                                               ushort* __restrict__ Hb, int M, int FP) {
    constexpr int KP = 320;
    constexpr int K  = 300;
    __shared__ __align__(16) ushort AsH[128][40];
    __shared__ __align__(16) ushort BsH[NT * 16][40];

    constexpr int NK = KP / 32;
    constexpr int BCH = (NT * 64 + 255) / 256;

    const int tid = threadIdx.x;
    const int lane = tid & 63;
    const int w = tid >> 6;
    const int brow = blockIdx.x * 128;

    f32x4 acc[2][NT];
    #pragma unroll
    for (int mt = 0; mt < 2; ++mt)
        #pragma unroll
        for (int nt = 0; nt < NT; ++nt)
            acc[mt][nt] = (f32x4){0.f, 0.f, 0.f, 0.f};

    const int ar = tid >> 1;
    const int aq = (tid & 1) * 2;
    const bool arow_ok = (brow + ar) < M;
    const size_t arow_off = (size_t)(brow + ar) * K;

    float4 rAf[2][2];
    short8 rBh[BCH];

    auto load_regs = [&](int kt) {
        const int k0 = kt * 32;
        #pragma unroll
        for (int qq = 0; qq < 2; ++qq) {
            int cb = k0 + (aq + qq) * 8;
            float4 z4 = {0.f, 0.f, 0.f, 0.f};
            rAf[qq][0] = z4;
            rAf[qq][1] = z4;
            if (arow_ok) {
                if (cb + 8 <= K) {
                    rAf[qq][0] = *(const float4*)(const void*)(Af + arow_off + cb);
                    rAf[qq][1] = *(const float4*)(const void*)(Af + arow_off + cb + 4);
                } else if (cb < K) {  // cb == 296: cols 296..299 valid
                    rAf[qq][0] = *(const float4*)(const void*)(Af + arow_off + cb);
                }
            }
        }
        #pragma unroll
        for (int c = 0; c < BCH; ++c) {
            int i = tid + c * 256;
            if (i < NT * 64) {
                int r = i >> 2;
                int q = i & 3;
                rBh[c] = *(const short8*)(const void*)(Bhi + (size_t)r * KP + k0 + q * 8);
            }
        }
    };
    auto write_lds = [&]() {
        #pragma unroll
        for (int qq = 0; qq < 2; ++qq) {
            int q = aq + qq;
            float v[8] = {rAf[qq][0].x, rAf[qq][0].y, rAf[qq][0].z, rAf[qq][0].w,
                          rAf[qq][1].x, rAf[qq][1].y, rAf[qq][1].z, rAf[qq][1].w};
            u16x8 h8;
            #pragma unroll
            for (int j = 0; j < 8; ++j) h8[j] = bf16_rne(v[j]);
            *(u16x8*)(void*)&AsH[ar][q * 8] = h8;
        }
        #pragma unroll
        for (int c = 0; c < BCH; ++c) {
            int i = tid + c * 256;
            if (i < NT * 64) {
                int r = i >> 2;
                int q = i & 3;
                *(short8*)(void*)&BsH[r][q * 8] = rBh[c];
            }
        }
    };

    load_regs(0);
    for (int kt = 0; kt < NK; ++kt) {
        write_lds();
        __syncthreads();
        if (kt + 1 < NK) load_regs(kt + 1);

        const int fr = lane & 15;
        const int fk = (lane >> 4) * 8;
        short8 ah[2];
        #pragma unroll
        for (int mt = 0; mt < 2; ++mt)
            ah[mt] = *(const short8*)(const void*)&AsH[w * 32 + mt * 16 + fr][fk];
        #pragma unroll
        for (int nt = 0; nt < NT; ++nt) {
            short8 bh = *(const short8*)(const void*)&BsH[nt * 16 + fr][fk];
            #pragma unroll
            for (int mt = 0; mt < 2; ++mt)
                acc[mt][nt] = __builtin_amdgcn_mfma_f32_16x16x32_bf16(ah[mt], bh, acc[mt][nt], 0, 0, 0);
        }
        __syncthreads();
    }

    const int fr = lane & 15;
    const int fq = lane >> 4;
    #pragma unroll
    for (int mt = 0; mt < 2; ++mt)
        #pragma unroll
        for (int nt = 0; nt < NT; ++nt) {
            int col = nt * 16 + fr;
            if (col < FP) {
                #pragma unroll
                for (int r = 0; r < 4; ++r) {
                    int row = brow + w * 32 + mt * 16 + fq * 4 + r;
                    if (row < M) Hb[(size_t)row * FP + col] = bf16_rne(acc[mt][nt][r]);
                }
            }
        }
}

// ---------------------------------------------------------------------------
// 1-term bf16 MFMA GEMM (layers 2-6). H out bf16, stride FP.
// ---------------------------------------------------------------------------
template <int KP, int NT>
__global__ __launch_bounds__(256) void gemm_bf16(const ushort* __restrict__ Ahi,
                                                 const ushort* __restrict__ Bhi,
                                                 ushort* __restrict__ Hb, int M, int FP) {
    __shared__ __align__(16) ushort AsH[128][40];
    __shared__ __align__(16) ushort BsH[NT * 16][40];

    constexpr int NK = KP / 32;
    constexpr int BCH = (NT * 64 + 255) / 256;

    const int tid = threadIdx.x;
    const int lane = tid & 63;
    const int w = tid >> 6;
    const int brow = blockIdx.x * 128;

    f32x4 acc[2][NT];
    #pragma unroll
    for (int mt = 0; mt < 2; ++mt)
        #pragma unroll
        for (int nt = 0; nt < NT; ++nt)
            acc[mt][nt] = (f32x4){0.f, 0.f, 0.f, 0.f};

    const int ar = tid >> 1;
    const int aq = (tid & 1) * 2;
    const bool arow_ok = (brow + ar) < M;
    const size_t arow_off = (size_t)(brow + ar) * KP;

    const short8 zz = {0, 0, 0, 0, 0, 0, 0, 0};
    short8 rAh[2], rBh[BCH];

    auto load_regs = [&](int kt) {
        const int k0 = kt * 32;
        #pragma unroll
        for (int qq = 0; qq < 2; ++qq) {
            int q = aq + qq;
            rAh[qq] = arow_ok ? *(const short8*)(const void*)(Ahi + arow_off + k0 + q * 8) : zz;
        }
        #pragma unroll
        for (int c = 0; c < BCH; ++c) {
            int i = tid + c * 256;
            if (i < NT * 64) {
                int r = i >> 2;
                int q = i & 3;
                rBh[c] = *(const short8*)(const void*)(Bhi + (size_t)r * KP + k0 + q * 8);
            }
        }
    };
    auto write_lds = [&]() {
        #pragma unroll
        for (int qq = 0; qq < 2; ++qq) {
            int q = aq + qq;
            *(short8*)(void*)&AsH[ar][q * 8] = rAh[qq];
        }
        #pragma unroll
        for (int c = 0; c < BCH; ++c) {
            int i = tid + c * 256;
            if (i < NT * 64) {
                int r = i >> 2;
                int q = i & 3;
                *(short8*)(void*)&BsH[r][q * 8] = rBh[c];
            }
        }
    };

    load_regs(0);
    for (int kt = 0; kt < NK; ++kt) {
        write_lds();
        __syncthreads();
        if (kt + 1 < NK) load_regs(kt + 1);

        const int fr = lane & 15;
        const int fk = (lane >> 4) * 8;
        short8 ah[2];
        #pragma unroll
        for (int mt = 0; mt < 2; ++mt)
            ah[mt] = *(const short8*)(const void*)&AsH[w * 32 + mt * 16 + fr][fk];
        #pragma unroll
        for (int nt = 0; nt < NT; ++nt) {
            short8 bh = *(const short8*)(const void*)&BsH[nt * 16 + fr][fk];
            #pragma unroll
            for (int mt = 0; mt < 2; ++mt)
                acc[mt][nt] = __builtin_amdgcn_mfma_f32_16x16x32_bf16(ah[mt], bh, acc[mt][nt], 0, 0, 0);
        }
        __syncthreads();
    }

    const int fr = lane & 15;
    const int fq = lane >> 4;
    #pragma unroll
    for (int mt = 0; mt < 2; ++mt)
        #pragma unroll
        for (int nt = 0; nt < NT; ++nt) {
            int col = nt * 16 + fr;
            if (col < FP) {
                #pragma unroll
                for (int r = 0; r < 4; ++r) {
                    int row = brow + w * 32 + mt * 16 + fq * 4 + r;
                    if (row < M) Hb[(size_t)row * FP + col] = bf16_rne(acc[mt][nt][r]);
                }
            }
        }
}

// ---------------------------------------------------------------------------
// Fused aggregation + bias + activation, bf16 H gather, sub-wave per node.
// Output (KPOUT>0): bf16 hi. KPOUT==0: f32 out.
// ---------------------------------------------------------------------------
template <int ACT, int F, int FP, int KPOUT, int SW>
__global__ __launch_bounds__(256) void agg_act(const ushort* __restrict__ Hb,
                                               const int* __restrict__ row_start,
                                               const int* __restrict__ esrc,
                                               const float* __restrict__ bias,
                                               float* __restrict__ outF,
                                               ushort* __restrict__ ohi) {
    constexpr int CH = FP / 8;
    constexpr int NPB = 256 / SW;
    static_assert(CH <= SW, "chunks must fit sub-wave");

    const int t = threadIdx.x;
    const int sub = t / SW;
    const int subl = t - sub * SW;
    const int v = blockIdx.x * NPB + sub;
    if (v >= N_NODES) return;

    const int e0 = row_start[v];
    const int e1 = row_start[v + 1];
    const bool al = subl < CH;
    const uint4v* Hc = (const uint4v*)Hb;

    float a[8] = {0.f, 0.f, 0.f, 0.f, 0.f, 0.f, 0.f, 0.f};

    #define ACCUM(rr)                                            \
        {                                                        \
            _Pragma("unroll")                                    \
            for (int k = 0; k < 4; ++k) {                        \
                uint u = (rr)[k];                                \
                a[2 * k]     += __uint_as_float(u << 16);        \
                a[2 * k + 1] += __uint_as_float(u & 0xFFFF0000u);\
            }                                                    \
        }

    int e = e0;
    for (; e + 8 <= e1; e += 8) {
        int s0 = esrc[e + 0], s1 = esrc[e + 1], s2 = esrc[e + 2], s3 = esrc[e + 3];
        int s4 = esrc[e + 4], s5 = esrc[e + 5], s6 = esrc[e + 6], s7 = esrc[e + 7];
        if (al) {
            uint4v r0 = Hc[(size_t)s0 * CH + subl];
            uint4v r1 = Hc[(size_t)s1 * CH + subl];
            uint4v r2 = Hc[(size_t)s2 * CH + subl];
            uint4v r3 = Hc[(size_t)s3 * CH + subl];
            uint4v r4 = Hc[(size_t)s4 * CH + subl];
            uint4v r5 = Hc[(size_t)s5 * CH + subl];
            uint4v r6 = Hc[(size_t)s6 * CH + subl];
            uint4v r7 = Hc[(size_t)s7 * CH + subl];
            ACCUM(r0) ACCUM(r1) ACCUM(r2) ACCUM(r3)
            ACCUM(r4) ACCUM(r5) ACCUM(r6) ACCUM(r7)
        }
    }
    if (e + 4 <= e1) {
        int s0 = esrc[e + 0], s1 = esrc[e + 1], s2 = esrc[e + 2], s3 = esrc[e + 3];
        if (al) {
            uint4v r0 = Hc[(size_t)s0 * CH + subl];
            uint4v r1 = Hc[(size_t)s1 * CH + subl];
            uint4v r2 = Hc[(size_t)s2 * CH + subl];
            uint4v r3 = Hc[(size_t)s3 * CH + subl];
            ACCUM(r0) ACCUM(r1) ACCUM(r2) ACCUM(r3)
        }
        e += 4;
    }
    for (; e < e1; ++e) {
        int s = esrc[e];
        if (al) {
            uint4v r = Hc[(size_t)s * CH + subl];
            ACCUM(r)
        }
    }
    #undef ACCUM

    const int jb = subl * 8;
    #pragma unroll
    for (int k = 0; k < 8; ++k) {
        int j = jb + k;
        a[k] += (al && j < F) ? bias[j] : 0.f;
    }

    float res[8];
    if (ACT == 0) {
        #pragma unroll
        for (int k = 0; k < 8; ++k)
            res[k] = (a[k] >= 0.f) ? a[k] : 0.01f * a[k];
    } else {
        float m = -INFINITY;
        #pragma unroll
        for (int k = 0; k < 8; ++k) {
            int j = jb + k;
            if (al && j < F) m = fmaxf(m, a[k]);
        }
        if (SW > 1) {
            #pragma unroll
            for (int off = SW / 2; off > 0; off >>= 1) m = fmaxf(m, __shfl_xor(m, off));
        }
        float p[8];
        float s = 0.f;
        #pragma unroll
        for (int k = 0; k < 8; ++k) {
            int j = jb + k;
            if (al && j < F) { p[k] = expf(a[k] - m); s += p[k]; } else p[k] = 0.f;
        }
        if (SW > 1) {
            #pragma unroll
            for (int off = SW / 2; off > 0; off >>= 1) s += __shfl_xor(s, off);
        }
        if (ACT == 1) {
            float inv = 1.f / s;
            #pragma unroll
            for (int k = 0; k < 8; ++k) res[k] = p[k] * inv;
        } else {
            float ls = logf(s);
            #pragma unroll
            for (int k = 0; k < 8; ++k) res[k] = a[k] - m - ls;
        }
    }

    if (KPOUT == 0) {
        float* orow = outF + (size_t)v * F;
        #pragma unroll
        for (int k = 0; k < 8; ++k) {
            int j = jb + k;
            if (al && j < F) orow[j] = res[k];
        }
    } else {
        if (jb < KPOUT) {
            u16x4 h4a = {0, 0, 0, 0}, h4b = {0, 0, 0, 0};
            #pragma unroll
            for (int k = 0; k < 4; ++k) {
                int j = jb + k;
                h4a[k] = bf16_rne((j < F) ? res[k] : 0.f);
            }
            #pragma unroll
            for (int k = 0; k < 4; ++k) {
                int j = jb + 4 + k;
                h4b[k] = bf16_rne((j < F) ? res[4 + k] : 0.f);
            }
            size_t o = (size_t)v * KPOUT + jb;
            *(u16x4*)(void*)(ohi + o) = h4a;
            *(u16x4*)(void*)(ohi + o + 4) = h4b;
        }
    }
}

// ---------------------------------------------------------------------------
// Host launch
// ---------------------------------------------------------------------------
static inline size_t align_up(size_t x, size_t a) { return (x + a - 1) & ~(a - 1); }

extern "C" void kernel_launch(void* const* d_in, const int* in_sizes, int n_in,
                              void* d_out, int out_size, void* d_ws, size_t ws_size,
                              hipStream_t stream) {
    const float* features = (const float*)d_in[0];
    const int* src = (const int*)d_in[1];
    const int* dst = (const int*)d_in[2];
    const float* W[6];
    const float* b[6];
    for (int l = 0; l < 6; ++l) {
        W[l] = (const float*)d_in[3 + 2 * l];
        b[l] = (const float*)d_in[4 + 2 * l];
    }

    const int fout[6] = {200, 150, 100, 50, 25, 3};
    const int KPin[6] = {320, 224, 160, 128, 64, 32};
    const int NPl[6]  = {208, 160, 112, 64, 32, 16};   // NT*16
    const int FPl[6]  = {200, 152, 104, 56, 32, 8};    // bf16 H row stride

    // workspace layout
    char* ws = (char*)d_ws;
    size_t off = 0;
    int* row_start  = (int*)(ws + off); off = align_up(off + (N_NODES + 1) * sizeof(int), 256);
    int* cursor     = (int*)(ws + off); off = align_up(off + (N_NODES + 1) * sizeof(int), 256);
    int* esrc       = (int*)(ws + off); off = align_up(off + N_EDGES * sizeof(int), 256);
    int* blockState = (int*)(ws + off); off = align_up(off + 64 * sizeof(int), 256);
    ushort* Wthi[6];
    for (int l = 0; l < 6; ++l) {
        Wthi[l] = (ushort*)(ws + off); off = align_up(off + (size_t)NPl[l] * KPin[l] * 2, 256);
    }
    ushort* Xhi = (ushort*)(ws + off); off = align_up(off + (size_t)N_NODES * 224 * 2, 256);
    ushort* Hb  = (ushort*)(ws + off); off = align_up(off + (size_t)N_NODES * 200 * 2, 256);
    (void)ws_size;

    // --- fused setup: zero + W conversion only ---
    {
        WtDescs wd;
        const int fin[6] = {300, 200, 150, 100, 50, 25};
        for (int l = 0; l < 6; ++l)
            wd.d[l] = WtDesc{W[l], Wthi[l], fin[l], fout[l], KPin[l], NPl[l]};
        setup_fused<<<2116, 256, 0, stream>>>(cursor, blockState, wd);
    }

    // --- CSR build ---
    count_kernel<<<(N_EDGES + 255) / 256, 256, 0, stream>>>(dst, cursor, N_EDGES);
    scan_lookback<<<(N_NODES + 1023) / 1024, 256, 0, stream>>>(cursor, row_start, cursor,
                                                               blockState, N_NODES, N_EDGES);
    fill_kernel<<<(N_EDGES + 255) / 256, 256, 0, stream>>>(src, dst, cursor, esrc, N_EDGES);

    const int gy = (N_NODES + 127) / 128;  // 391

    // L1: GEMM reads f32 features directly (in-register bf16 conversion)
    gemm_l1<13><<<gy, 256, 0, stream>>>(features, Wthi[0], Hb, N_NODES, FPl[0]);
    agg_act<0, 200, 200, 224, 32><<<(N_NODES + 7) / 8, 256, 0, stream>>>(Hb, row_start, esrc, b[0], nullptr, Xhi);

    gemm_bf16<224, 10><<<gy, 256, 0, stream>>>(Xhi, Wthi[1], Hb, N_NODES, FPl[1]);
    agg_act<1, 150, 152, 160, 32><<<(N_NODES + 7) / 8, 256, 0, stream>>>(Hb, row_start, esrc, b[1], nullptr, Xhi);

    gemm_bf16<160, 7><<<gy, 256, 0, stream>>>(Xhi, Wthi[2], Hb, N_NODES, FPl[2]);
    agg_act<0, 100, 104, 128, 16><<<(N_NODES + 15) / 16, 256, 0, stream>>>(Hb, row_start, esrc, b[2], nullptr, Xhi);

    gemm_bf16<128, 4><<<gy, 256, 0, stream>>>(Xhi, Wthi[3], Hb, N_NODES, FPl[3]);
    agg_act<1, 50, 56, 64, 8><<<(N_NODES + 31) / 32, 256, 0, stream>>>(Hb, row_start, esrc, b[3], nullptr, Xhi);

    gemm_bf16<64, 2><<<gy, 256, 0, stream>>>(Xhi, Wthi[4], Hb, N_NODES, FPl[4]);
    agg_act<0, 25, 32, 32, 4><<<(N_NODES + 63) / 64, 256, 0, stream>>>(Hb, row_start, esrc, b[4], nullptr, Xhi);

    gemm_bf16<32, 1><<<gy, 256, 0, stream>>>(Xhi, Wthi[5], Hb, N_NODES, FPl[5]);
    agg_act<2, 3, 8, 0, 1><<<(N_NODES + 255) / 256, 256, 0, stream>>>(Hb, row_start, esrc, b[5], (float*)d_out, nullptr);

    (void)out_size; (void)n_in; (void)in_sizes;
}

// Round 12
// 242.088 us; speedup vs baseline: 1.1005x; 1.0799x over previous
//
#include <hip/hip_runtime.h>
#include <math.h>

#define N_NODES 50000
#define N_EDGES 262144

using short8  = __attribute__((ext_vector_type(8))) short;
using f32x4   = __attribute__((ext_vector_type(4))) float;
using u16x4   = __attribute__((ext_vector_type(4))) unsigned short;
using u16x8   = __attribute__((ext_vector_type(8))) unsigned short;
using uint4v  = __attribute__((ext_vector_type(4))) unsigned int;

// ---------------------------------------------------------------------------
// bf16 helpers (RNE)
// ---------------------------------------------------------------------------
__device__ __forceinline__ ushort bf16_rne(float x) {
    uint u = __float_as_uint(x);
    uint r = (u + 0x7FFFu + ((u >> 16) & 1u)) >> 16;
    return (ushort)r;
}

struct WtDesc { const float* W; ushort* hi; int K, N, KP, NP; };
struct WtDescs { WtDesc d[6]; };

// ---------------------------------------------------------------------------
// Fused setup: zero cursor+blockState | convert W (hi) | convert features (hi)
// blocks [0,196): zero; [196,2116): convert_w; [2116, 2116+7813): convert_x
// ---------------------------------------------------------------------------
__global__ __launch_bounds__(256) void setup_fused(int* __restrict__ cursor,
                                                   int* __restrict__ blockState,
                                                   WtDescs all,
                                                   const float* __restrict__ X,
                                                   ushort* __restrict__ hi) {
    const int b = blockIdx.x;
    const int t = threadIdx.x;
    if (b < 196) {
        int i = b * 256 + t;
        if (i < N_NODES) cursor[i] = 0;
        if (b == 0 && t < 64) blockState[t] = 0;
    } else if (b < 2116) {
        int bb = b - 196;
        WtDesc d = all.d[bb / 320];
        int total = d.NP * d.KP;
        for (int idx = (bb % 320) * 256 + t; idx < total; idx += 320 * 256) {
            int n = idx / d.KP;
            int k = idx - n * d.KP;
            float v = (n < d.N && k < d.K) ? d.W[(size_t)k * d.N + n] : 0.f;
            d.hi[idx] = bf16_rne(v);
        }
    } else {
        int idx = (b - 2116) * 256 + t;       // N_NODES*40 ushort8 jobs
        if (idx >= N_NODES * 40) return;
        int row = idx / 40;
        int c = idx - row * 40;
        u16x8 h8 = {0, 0, 0, 0, 0, 0, 0, 0};
        const float* xr = X + (size_t)row * 300 + c * 8;
        if (c < 37) {
            float4 v0 = *(const float4*)(const void*)(xr);
            float4 v1 = *(const float4*)(const void*)(xr + 4);
            h8[0] = bf16_rne(v0.x); h8[1] = bf16_rne(v0.y);
            h8[2] = bf16_rne(v0.z); h8[3] = bf16_rne(v0.w);
            h8[4] = bf16_rne(v1.x); h8[5] = bf16_rne(v1.y);
            h8[6] = bf16_rne(v1.z); h8[7] = bf16_rne(v1.w);
        } else if (c == 37) {
            float4 v0 = *(const float4*)(const void*)(xr);  // cols 296..299
            h8[0] = bf16_rne(v0.x); h8[1] = bf16_rne(v0.y);
            h8[2] = bf16_rne(v0.z); h8[3] = bf16_rne(v0.w);
        }
        *(u16x8*)(void*)(hi + (size_t)row * 320 + c * 8) = h8;
    }
}

// ---------------------------------------------------------------------------
// CSR build
// ---------------------------------------------------------------------------
__global__ void count_kernel(const int* __restrict__ dst, int* __restrict__ deg, int E) {
    int e = blockIdx.x * 256 + threadIdx.x;
    if (e < E) atomicAdd(&deg[dst[e]], 1);
}

// single-kernel decoupled-lookback exclusive scan (49 blocks x 1024 elems)
__global__ __launch_bounds__(256) void scan_lookback(const int* __restrict__ deg,
                                                     int* __restrict__ row_start,
                                                     int* __restrict__ cursor,
                                                     int* __restrict__ blockState,
                                                     int n, int total) {
    __shared__ int wsum[4];
    __shared__ int s_off;
    const int b = blockIdx.x;
    const int t = threadIdx.x;
    const int i0 = b * 1024 + t * 4;
    int x0 = 0, x1 = 0, x2 = 0, x3 = 0;
    if (i0 + 3 < n) {
        int4 v = *(const int4*)(const void*)(deg + i0);
        x0 = v.x; x1 = v.y; x2 = v.z; x3 = v.w;
    } else {
        if (i0 + 0 < n) x0 = deg[i0 + 0];
        if (i0 + 1 < n) x1 = deg[i0 + 1];
        if (i0 + 2 < n) x2 = deg[i0 + 2];
        if (i0 + 3 < n) x3 = deg[i0 + 3];
    }
    int s = x0 + x1 + x2 + x3;
    int lane = t & 63;
    int wid = t >> 6;
    int incl = s;
    #pragma unroll
    for (int off = 1; off < 64; off <<= 1) {
        int u = __shfl_up(incl, off);
        if (lane >= off) incl += u;
    }
    if (lane == 63) wsum[wid] = incl;
    __syncthreads();
    int woff = 0;
    #pragma unroll
    for (int k = 0; k < 4; ++k)
        if (k < wid) woff += wsum[k];
    int texcl = woff + incl - s;

    if (t == 0) {
        int bs = wsum[0] + wsum[1] + wsum[2] + wsum[3];
        atomicExch(&blockState[b], (bs << 2) | 1);
        int off = 0;
        for (int pb = b - 1; pb >= 0; --pb) {
            int st;
            do { st = atomicAdd(&blockState[pb], 0); } while ((st & 3) == 0);
            off += (st >> 2);
            if ((st & 3) == 2) break;
        }
        atomicExch(&blockState[b], ((off + bs) << 2) | 2);
        s_off = off;
    }
    __syncthreads();
    int off = s_off;

    if (i0 + 3 < n) {
        int4 o;
        o.x = off + texcl;
        o.y = off + texcl + x0;
        o.z = off + texcl + x0 + x1;
        o.w = off + texcl + x0 + x1 + x2;
        *(int4*)(void*)(row_start + i0) = o;
        *(int4*)(void*)(cursor + i0) = o;
    } else {
        int vals[4] = {off + texcl, off + texcl + x0, off + texcl + x0 + x1,
                       off + texcl + x0 + x1 + x2};
        #pragma unroll
        for (int k = 0; k < 4; ++k)
            if (i0 + k < n) { row_start[i0 + k] = vals[k]; cursor[i0 + k] = vals[k]; }
    }
    if (b == 0 && t == 0) row_start[n] = total;
}

__global__ void fill_kernel(const int* __restrict__ src, const int* __restrict__ dst,
                            int* __restrict__ cursor, int* __restrict__ esrc, int E) {
    int e = blockIdx.x * 256 + threadIdx.x;
    if (e < E) {
        int d = dst[e];
        int pos = atomicAdd(&cursor[d], 1);
        esrc[pos] = src[e];
    }
}

// ---------------------------------------------------------------------------
// 1-term bf16 MFMA GEMM (all layers). H out bf16, stride FP.
// Full-N per block, register-prefetch pipeline, A fetched once per layer.
// ---------------------------------------------------------------------------
template <int KP, int NT>
__global__ __launch_bounds__(256) void gemm_bf16(const ushort* __restrict__ Ahi,
                                                 const ushort* __restrict__ Bhi,
                                                 ushort* __restrict__ Hb, int M, int FP) {
    __shared__ __align__(16) ushort AsH[128][40];
    __shared__ __align__(16) ushort BsH[NT * 16][40];

    constexpr int NK = KP / 32;
    constexpr int BCH = (NT * 64 + 255) / 256;

    const int tid = threadIdx.x;
    const int lane = tid & 63;
    const int w = tid >> 6;
    const int brow = blockIdx.x * 128;

    f32x4 acc[2][NT];
    #pragma unroll
    for (int mt = 0; mt < 2; ++mt)
        #pragma unroll
        for (int nt = 0; nt < NT; ++nt)
            acc[mt][nt] = (f32x4){0.f, 0.f, 0.f, 0.f};

    const int ar = tid >> 1;
    const int aq = (tid & 1) * 2;
    const bool arow_ok = (brow + ar) < M;
    const size_t arow_off = (size_t)(brow + ar) * KP;

    const short8 zz = {0, 0, 0, 0, 0, 0, 0, 0};
    short8 rAh[2], rBh[BCH];

    auto load_regs = [&](int kt) {
        const int k0 = kt * 32;
        #pragma unroll
        for (int qq = 0; qq < 2; ++qq) {
            int q = aq + qq;
            rAh[qq] = arow_ok ? *(const short8*)(const void*)(Ahi + arow_off + k0 + q * 8) : zz;
        }
        #pragma unroll
        for (int c = 0; c < BCH; ++c) {
            int i = tid + c * 256;
            if (i < NT * 64) {
                int r = i >> 2;
                int q = i & 3;
                rBh[c] = *(const short8*)(const void*)(Bhi + (size_t)r * KP + k0 + q * 8);
            }
        }
    };
    auto write_lds = [&]() {
        #pragma unroll
        for (int qq = 0; qq < 2; ++qq) {
            int q = aq + qq;
            *(short8*)(void*)&AsH[ar][q * 8] = rAh[qq];
        }
        #pragma unroll
        for (int c = 0; c < BCH; ++c) {
            int i = tid + c * 256;
            if (i < NT * 64) {
                int r = i >> 2;
                int q = i & 3;
                *(short8*)(void*)&BsH[r][q * 8] = rBh[c];
            }
        }
    };

    load_regs(0);
    for (int kt = 0; kt < NK; ++kt) {
        write_lds();
        __syncthreads();
        if (kt + 1 < NK) load_regs(kt + 1);

        const int fr = lane & 15;
        const int fk = (lane >> 4) * 8;
        short8 ah[2];
        #pragma unroll
        for (int mt = 0; mt < 2; ++mt)
            ah[mt] = *(const short8*)(const void*)&AsH[w * 32 + mt * 16 + fr][fk];
        #pragma unroll
        for (int nt = 0; nt < NT; ++nt) {
            short8 bh = *(const short8*)(const void*)&BsH[nt * 16 + fr][fk];
            #pragma unroll
            for (int mt = 0; mt < 2; ++mt)
                acc[mt][nt] = __builtin_amdgcn_mfma_f32_16x16x32_bf16(ah[mt], bh, acc[mt][nt], 0, 0, 0);
        }
        __syncthreads();
    }

    const int fr = lane & 15;
    const int fq = lane >> 4;
    #pragma unroll
    for (int mt = 0; mt < 2; ++mt)
        #pragma unroll
        for (int nt = 0; nt < NT; ++nt) {
            int col = nt * 16 + fr;
            if (col < FP) {
                #pragma unroll
                for (int r = 0; r < 4; ++r) {
                    int row = brow + w * 32 + mt * 16 + fq * 4 + r;
                    if (row < M) Hb[(size_t)row * FP + col] = bf16_rne(acc[mt][nt][r]);
                }
            }
        }
}

// ---------------------------------------------------------------------------
// Fused aggregation + bias + activation, bf16 H gather, sub-wave per node.
// Output (KPOUT>0): bf16 hi. KPOUT==0: f32 out.
// ---------------------------------------------------------------------------
template <int ACT, int F, int FP, int KPOUT, int SW>
__global__ __launch_bounds__(256) void agg_act(const ushort* __restrict__ Hb,
                                               const int* __restrict__ row_start,
                                               const int* __restrict__ esrc,
                                               const float* __restrict__ bias,
                                               float* __restrict__ outF,
                                               ushort* __restrict__ ohi) {
    constexpr int CH = FP / 8;
    constexpr int NPB = 256 / SW;
    static_assert(CH <= SW, "chunks must fit sub-wave");

    const int t = threadIdx.x;
    const int sub = t / SW;
    const int subl = t - sub * SW;
    const int v = blockIdx.x * NPB + sub;
    if (v >= N_NODES) return;

    const int e0 = row_start[v];
    const int e1 = row_start[v + 1];
    const bool al = subl < CH;
    const uint4v* Hc = (const uint4v*)Hb;

    float a[8] = {0.f, 0.f, 0.f, 0.f, 0.f, 0.f, 0.f, 0.f};

    #define ACCUM(rr)                                            \
        {                                                        \
            _Pragma("unroll")                                    \
            for (int k = 0; k < 4; ++k) {                        \
                uint u = (rr)[k];                                \
                a[2 * k]     += __uint_as_float(u << 16);        \
                a[2 * k + 1] += __uint_as_float(u & 0xFFFF0000u);\
            }                                                    \
        }

    int e = e0;
    for (; e + 8 <= e1; e += 8) {
        int s0 = esrc[e + 0], s1 = esrc[e + 1], s2 = esrc[e + 2], s3 = esrc[e + 3];
        int s4 = esrc[e + 4], s5 = esrc[e + 5], s6 = esrc[e + 6], s7 = esrc[e + 7];
        if (al) {
            uint4v r0 = Hc[(size_t)s0 * CH + subl];
            uint4v r1 = Hc[(size_t)s1 * CH + subl];
            uint4v r2 = Hc[(size_t)s2 * CH + subl];
            uint4v r3 = Hc[(size_t)s3 * CH + subl];
            uint4v r4 = Hc[(size_t)s4 * CH + subl];
            uint4v r5 = Hc[(size_t)s5 * CH + subl];
            uint4v r6 = Hc[(size_t)s6 * CH + subl];
            uint4v r7 = Hc[(size_t)s7 * CH + subl];
            ACCUM(r0) ACCUM(r1) ACCUM(r2) ACCUM(r3)
            ACCUM(r4) ACCUM(r5) ACCUM(r6) ACCUM(r7)
        }
    }
    if (e + 4 <= e1) {
        int s0 = esrc[e + 0], s1 = esrc[e + 1], s2 = esrc[e + 2], s3 = esrc[e + 3];
        if (al) {
            uint4v r0 = Hc[(size_t)s0 * CH + subl];
            uint4v r1 = Hc[(size_t)s1 * CH + subl];
            uint4v r2 = Hc[(size_t)s2 * CH + subl];
            uint4v r3 = Hc[(size_t)s3 * CH + subl];
            ACCUM(r0) ACCUM(r1) ACCUM(r2) ACCUM(r3)
        }
        e += 4;
    }
    for (; e < e1; ++e) {
        int s = esrc[e];
        if (al) {
            uint4v r = Hc[(size_t)s * CH + subl];
            ACCUM(r)
        }
    }
    #undef ACCUM

    const int jb = subl * 8;
    #pragma unroll
    for (int k = 0; k < 8; ++k) {
        int j = jb + k;
        a[k] += (al && j < F) ? bias[j] : 0.f;
    }

    float res[8];
    if (ACT == 0) {
        #pragma unroll
        for (int k = 0; k < 8; ++k)
            res[k] = (a[k] >= 0.f) ? a[k] : 0.01f * a[k];
    } else {
        float m = -INFINITY;
        #pragma unroll
        for (int k = 0; k < 8; ++k) {
            int j = jb + k;
            if (al && j < F) m = fmaxf(m, a[k]);
        }
        if (SW > 1) {
            #pragma unroll
            for (int off = SW / 2; off > 0; off >>= 1) m = fmaxf(m, __shfl_xor(m, off));
        }
        float p[8];
        float s = 0.f;
        #pragma unroll
        for (int k = 0; k < 8; ++k) {
            int j = jb + k;
            if (al && j < F) { p[k] = expf(a[k] - m); s += p[k]; } else p[k] = 0.f;
        }
        if (SW > 1) {
            #pragma unroll
            for (int off = SW / 2; off > 0; off >>= 1) s += __shfl_xor(s, off);
        }
        if (ACT == 1) {
            float inv = 1.f / s;
            #pragma unroll
            for (int k = 0; k < 8; ++k) res[k] = p[k] * inv;
        } else {
            float ls = logf(s);
            #pragma unroll
            for (int k = 0; k < 8; ++k) res[k] = a[k] - m - ls;
        }
    }

    if (KPOUT == 0) {
        float* orow = outF + (size_t)v * F;
        #pragma unroll
        for (int k = 0; k < 8; ++k) {
            int j = jb + k;
            if (al && j < F) orow[j] = res[k];
        }
    } else {
        if (jb < KPOUT) {
            u16x4 h4a = {0, 0, 0, 0}, h4b = {0, 0, 0, 0};
            #pragma unroll
            for (int k = 0; k < 4; ++k) {
                int j = jb + k;
                h4a[k] = bf16_rne((j < F) ? res[k] : 0.f);
            }
            #pragma unroll
            for (int k = 0; k < 4; ++k) {
                int j = jb + 4 + k;
                h4b[k] = bf16_rne((j < F) ? res[4 + k] : 0.f);
            }
            size_t o = (size_t)v * KPOUT + jb;
            *(u16x4*)(void*)(ohi + o) = h4a;
            *(u16x4*)(void*)(ohi + o + 4) = h4b;
        }
    }
}

// ---------------------------------------------------------------------------
// Host launch
// ---------------------------------------------------------------------------
static inline size_t align_up(size_t x, size_t a) { return (x + a - 1) & ~(a - 1); }

extern "C" void kernel_launch(void* const* d_in, const int* in_sizes, int n_in,
                              void* d_out, int out_size, void* d_ws, size_t ws_size,
                              hipStream_t stream) {
    const float* features = (const float*)d_in[0];
    const int* src = (const int*)d_in[1];
    const int* dst = (const int*)d_in[2];
    const float* W[6];
    const float* b[6];
    for (int l = 0; l < 6; ++l) {
        W[l] = (const float*)d_in[3 + 2 * l];
        b[l] = (const float*)d_in[4 + 2 * l];
    }

    const int fout[6] = {200, 150, 100, 50, 25, 3};
    const int KPin[6] = {320, 224, 160, 128, 64, 32};
    const int NPl[6]  = {208, 160, 112, 64, 32, 16};   // NT*16
    const int FPl[6]  = {200, 152, 104, 56, 32, 8};    // bf16 H row stride

    // workspace layout
    char* ws = (char*)d_ws;
    size_t off = 0;
    int* row_start  = (int*)(ws + off); off = align_up(off + (N_NODES + 1) * sizeof(int), 256);
    int* cursor     = (int*)(ws + off); off = align_up(off + (N_NODES + 1) * sizeof(int), 256);
    int* esrc       = (int*)(ws + off); off = align_up(off + N_EDGES * sizeof(int), 256);
    int* blockState = (int*)(ws + off); off = align_up(off + 64 * sizeof(int), 256);
    ushort* Wthi[6];
    for (int l = 0; l < 6; ++l) {
        Wthi[l] = (ushort*)(ws + off); off = align_up(off + (size_t)NPl[l] * KPin[l] * 2, 256);
    }
    ushort* Xhi = (ushort*)(ws + off); off = align_up(off + (size_t)N_NODES * 320 * 2, 256);
    ushort* Hb  = (ushort*)(ws + off); off = align_up(off + (size_t)N_NODES * 200 * 2, 256);
    (void)ws_size;

    // --- fused setup ---
    {
        WtDescs wd;
        const int fin[6] = {300, 200, 150, 100, 50, 25};
        for (int l = 0; l < 6; ++l)
            wd.d[l] = WtDesc{W[l], Wthi[l], fin[l], fout[l], KPin[l], NPl[l]};
        setup_fused<<<2116 + (N_NODES * 40 + 255) / 256, 256, 0, stream>>>(
            cursor, blockState, wd, features, Xhi);
    }

    // --- CSR build ---
    count_kernel<<<(N_EDGES + 255) / 256, 256, 0, stream>>>(dst, cursor, N_EDGES);
    scan_lookback<<<(N_NODES + 1023) / 1024, 256, 0, stream>>>(cursor, row_start, cursor,
                                                               blockState, N_NODES, N_EDGES);
    fill_kernel<<<(N_EDGES + 255) / 256, 256, 0, stream>>>(src, dst, cursor, esrc, N_EDGES);

    const int gy = (N_NODES + 127) / 128;  // 391

    gemm_bf16<320, 13><<<gy, 256, 0, stream>>>(Xhi, Wthi[0], Hb, N_NODES, FPl[0]);
    agg_act<0, 200, 200, 224, 32><<<(N_NODES + 7) / 8, 256, 0, stream>>>(Hb, row_start, esrc, b[0], nullptr, Xhi);

    gemm_bf16<224, 10><<<gy, 256, 0, stream>>>(Xhi, Wthi[1], Hb, N_NODES, FPl[1]);
    agg_act<1, 150, 152, 160, 32><<<(N_NODES + 7) / 8, 256, 0, stream>>>(Hb, row_start, esrc, b[1], nullptr, Xhi);

    gemm_bf16<160, 7><<<gy, 256, 0, stream>>>(Xhi, Wthi[2], Hb, N_NODES, FPl[2]);
    agg_act<0, 100, 104, 128, 16><<<(N_NODES + 15) / 16, 256, 0, stream>>>(Hb, row_start, esrc, b[2], nullptr, Xhi);

    gemm_bf16<128, 4><<<gy, 256, 0, stream>>>(Xhi, Wthi[3], Hb, N_NODES, FPl[3]);
    agg_act<1, 50, 56, 64, 8><<<(N_NODES + 31) / 32, 256, 0, stream>>>(Hb, row_start, esrc, b[3], nullptr, Xhi);

    gemm_bf16<64, 2><<<gy, 256, 0, stream>>>(Xhi, Wthi[4], Hb, N_NODES, FPl[4]);
    agg_act<0, 25, 32, 32, 4><<<(N_NODES + 63) / 64, 256, 0, stream>>>(Hb, row_start, esrc, b[4], nullptr, Xhi);

    gemm_bf16<32, 1><<<gy, 256, 0, stream>>>(Xhi, Wthi[5], Hb, N_NODES, FPl[5]);
    agg_act<2, 3, 8, 0, 1><<<(N_NODES + 255) / 256, 256, 0, stream>>>(Hb, row_start, esrc, b[5], (float*)d_out, nullptr);

    (void)out_size; (void)n_in; (void)in_sizes;
}